// Round 7
// baseline (934.861 us; speedup 1.0000x reference)
//
#include <hip/hip_runtime.h>

// DeepTreeLSTM on MI355X (gfx950). Inputs fp32 (verified R3); dtype probe kept.
// Tree: 511 nodes, level d has 2^d nodes. h level-major: base_d = 256*(2^d-1)*256.
//
// Level kernel: one GEMM over child rows vs {F,I,O,U} weight groups; MFMA
// 16x16x32 C-layout puts child pairs (2p,2p+1) in one lane's reg pairs and all
// 4 groups of a hidden col in the same lane -> LSTM cell epilogue in-register.
// R6 post-mortem: 64KB LDS tile -> 2 blocks/CU -> 21.6% occupancy, latency-bound.
// R7: 64-row / 32KB tile + launch_bounds(256,4) -> 4 blocks/CU; 2D grid col-split
// keeps small levels >= 128 blocks.
//
// Workspace (<= ~119 MB):
//   h_all  bf16 [0,           66,977,792)
//   cbufA  bf16 [66,977,792, 100,532,224)   c for even levels (8,6,4,2,0)
//   cbufB  bf16 [100,532,224,117,309,440)   c for odd levels (7,5,3,1)
//   arena  bf16 [117,309,440,118,401,928)   converted weights/biases/emo
//   flag   int  [118,401,928,118,401,932)
//   x2     fp32 [118,401,936,118,958,992)

typedef __attribute__((ext_vector_type(8))) short short8;
typedef __attribute__((ext_vector_type(4))) float f32x4;

#define HB 256
#define BASE8 16711680   // 256*255*256

#define A_WIOU 0
#define A_UIOU 196608
#define A_BIOU 393216
#define A_UFW  393984
#define A_UFB  459520
#define A_WIN  459776
#define A_BIN  529408
#define A_WMID 529536
#define A_BMID 537728
#define A_WOUT 537792
#define A_BOUT 538048
#define A_EMO  538052
#define A_TOT  546244

__device__ __forceinline__ float b2f(short s){
  union { unsigned u; float f; } v; v.u = ((unsigned)(unsigned short)s) << 16; return v.f;
}
__device__ __forceinline__ short f2b(float f){
  union { float f; unsigned u; } v; v.f = f;
  unsigned r = v.u + 0x7fffu + ((v.u >> 16) & 1u);   // RNE
  return (short)(unsigned short)(r >> 16);
}
__device__ __forceinline__ float fsig(float x){ return 1.f / (1.f + __expf(-x)); }
__device__ __forceinline__ float ftanh(float x){
  x = fminf(fmaxf(x, -10.f), 10.f);
  float e = __expf(2.f * x);
  return (e - 1.f) / (e + 1.f);
}

// LDS A-tile: 64 rows x 256 k, XOR-swizzled 8-short groups (32 KB).
__device__ __forceinline__ int swz(int row, int g){   // g = k>>3
  return row * 256 + (((g ^ (row & 31)) & 31) << 3);
}

// ---------------- dtype probe ------------------------------------------------------------
__global__ __launch_bounds__(256)
void probe_kernel(const void* __restrict__ X, int* __restrict__ flag)
{
  __shared__ int sh[256];
  const int t = threadIdx.x;
  const unsigned short* p = (const unsigned short*)X;
  int cnt = 0;
  #pragma unroll
  for (int k = 0; k < 16; ++k){
    unsigned e = (p[t * 16 + k] >> 7) & 0xFFu;
    cnt += (e >= 0xC0u);
  }
  sh[t] = cnt; __syncthreads();
  for (int s = 128; s > 0; s >>= 1){ if (t < s) sh[t] += sh[t + s]; __syncthreads(); }
  if (t == 0) *flag = (sh[0] >= 16) ? 1 : 0;
}

// ---------------- convert params into bf16 arena -----------------------------------------
__global__ __launch_bounds__(256)
void conv_kernel(const void* s0, const void* s1, const void* s2, const void* s3,
                 const void* s4, const void* s5, const void* s6, const void* s7,
                 const void* s8, const void* s9, const void* s10, const void* s11,
                 short* __restrict__ arena, const int* __restrict__ flag)
{
  const int i = blockIdx.x * 256 + threadIdx.x;
  if (i >= A_TOT) return;
  const int bounds[13] = {A_WIOU, A_UIOU, A_BIOU, A_UFW, A_UFB, A_WIN, A_BIN,
                          A_WMID, A_BMID, A_WOUT, A_BOUT, A_EMO, A_TOT};
  const void* sp[12] = {s0,s1,s2,s3,s4,s5,s6,s7,s8,s9,s10,s11};
  int seg = 0;
  #pragma unroll
  for (int k = 1; k < 12; ++k) if (i >= bounds[k]) seg = k;
  const int j = i - bounds[seg];
  const float v = (*flag) ? ((const float*)sp[seg])[j] : b2f(((const short*)sp[seg])[j]);
  arena[i] = f2b(v);
}

// ---------------- leaf: 64 rows staged (fp32->bf16 inline), 4 col-slices x 3 gates -------
// grid (1024), block 256. Wave w: 64 rows x (16 hidden x 3 gates), col = s*64+w*16+l15.
// acc[4 rowtiles][3] = 48 f32/lane.
__global__ __launch_bounds__(256, 4)
void leaf_kernel(const void* __restrict__ X, const short* __restrict__ arena,
                 const int* __restrict__ flag,
                 short* __restrict__ hall, short* __restrict__ cout)
{
  __shared__ short At[16384];
  const int t = threadIdx.x, lane = t & 63, w = t >> 6;
  const int l15 = lane & 15, quad = lane >> 4;
  const int rowbase = 64 * blockIdx.x;                  // leaf-local row
  // leaf rows of one block are contiguous in X: batch = rowbase>>8, node 255+(row&255)
  const size_t grow0 = ((size_t)(rowbase >> 8) * 511 + 255 + (rowbase & 255)) * HB;
  const bool isf = (*flag) != 0;

  // stage 64 rows x 256 k (2048 groups of 8; 8 per thread)
  #pragma unroll
  for (int i = 0; i < 8; ++i){
    const int gi = i * 256 + t;
    const int row = gi >> 5, g = gi & 31;
    short8 v;
    if (isf){
      const float* p = (const float*)X + grow0 + (size_t)row * HB + g * 8;
      const float4 u = *(const float4*)p;
      const float4 q = *(const float4*)(p + 4);
      v[0]=f2b(u.x); v[1]=f2b(u.y); v[2]=f2b(u.z); v[3]=f2b(u.w);
      v[4]=f2b(q.x); v[5]=f2b(q.y); v[6]=f2b(q.z); v[7]=f2b(q.w);
    } else {
      v = *(const short8*)((const short*)X + grow0 + (size_t)row * HB + g * 8);
    }
    *(short8*)&At[swz(row, g)] = v;
  }
  __syncthreads();

  #pragma unroll
  for (int s = 0; s < 4; ++s){
    const int colh = s * 64 + w * 16 + l15;             // hidden col 0..255
    const short* pI = arena + A_WIOU + (size_t)colh * HB + quad * 8;
    const short* pO = pI + 65536;                       // 256*256
    const short* pU = pI + 131072;

    f32x4 acc[4][3];
    #pragma unroll
    for (int rt = 0; rt < 4; ++rt)
      #pragma unroll
      for (int g = 0; g < 3; ++g) acc[rt][g] = (f32x4){0.f,0.f,0.f,0.f};

    #pragma unroll
    for (int kk = 0; kk < 8; ++kk){
      const short8 bI = *(const short8*)(pI + kk * 32);
      const short8 bO = *(const short8*)(pO + kk * 32);
      const short8 bU = *(const short8*)(pU + kk * 32);
      #pragma unroll
      for (int rt = 0; rt < 4; ++rt){
        const int row = rt * 16 + l15;
        const short8 a = *(const short8*)&At[swz(row, kk * 4 + quad)];
        acc[rt][0] = __builtin_amdgcn_mfma_f32_16x16x32_bf16(a, bI, acc[rt][0], 0, 0, 0);
        acc[rt][1] = __builtin_amdgcn_mfma_f32_16x16x32_bf16(a, bO, acc[rt][1], 0, 0, 0);
        acc[rt][2] = __builtin_amdgcn_mfma_f32_16x16x32_bf16(a, bU, acc[rt][2], 0, 0, 0);
      }
    }

    const float bi = b2f(arena[A_BIOU + colh]);
    const float bo = b2f(arena[A_BIOU + 256 + colh]);
    const float bu = b2f(arena[A_BIOU + 512 + colh]);
    #pragma unroll
    for (int rt = 0; rt < 4; ++rt){
      const f32x4 vi = acc[rt][0], vo = acc[rt][1], vu = acc[rt][2];
      #pragma unroll
      for (int r = 0; r < 4; ++r){
        const int row = rowbase + rt * 16 + quad * 4 + r;
        const float ig = fsig(vi[r] + bi);
        const float og = fsig(vo[r] + bo);
        const float ug = ftanh(vu[r] + bu);
        const float cv = ig * ug;                       // c_in = 0
        const float hv = og * ftanh(cv);
        const size_t o = (size_t)row * HB + colh;
        hall[BASE8 + o] = f2b(hv);
        cout[o] = f2b(cv);
      }
    }
  }
}

// ---------------- level: 64 child rows staged, col-split x {F,I,O,U} ---------------------
// grid (childrows/64, 4/spb), block 256. Wave w: 64 rows x (16 hidden x 4 groups);
// acc[4][4] = 64 f32/lane. Col slice s in [blockIdx.y*spb, +spb).
__global__ __launch_bounds__(256, 4)
void level_kernel(const short* __restrict__ hch, const short* __restrict__ cch,
                  const short* __restrict__ arena,
                  short* __restrict__ hout, short* __restrict__ cout, int spb)
{
  __shared__ short At[16384];
  const int t = threadIdx.x, lane = t & 63, w = t >> 6;
  const int l15 = lane & 15, quad = lane >> 4;
  const int rowbase = 64 * blockIdx.x;                  // child rows
  const int pbase   = 32 * blockIdx.x;                  // parent rows

  #pragma unroll
  for (int i = 0; i < 8; ++i){
    const int gi = i * 256 + t;
    const int row = gi >> 5, g = gi & 31;
    *(short8*)&At[swz(row, g)] =
        *(const short8*)(hch + (size_t)(rowbase + row) * HB + g * 8);
  }
  __syncthreads();

  const int s0 = blockIdx.y * spb;
  for (int s = s0; s < s0 + spb; ++s){
    const int colh = s * 64 + w * 16 + l15;
    const short* pF = arena + A_UFW  + (size_t)colh * HB + quad * 8;
    const short* pI = arena + A_UIOU + (size_t)colh * HB + quad * 8;
    const short* pO = pI + 65536;
    const short* pU = pI + 131072;

    f32x4 acc[4][4];
    #pragma unroll
    for (int rt = 0; rt < 4; ++rt)
      #pragma unroll
      for (int g = 0; g < 4; ++g) acc[rt][g] = (f32x4){0.f,0.f,0.f,0.f};

    #pragma unroll
    for (int kk = 0; kk < 8; ++kk){
      const short8 bF = *(const short8*)(pF + kk * 32);
      const short8 bI = *(const short8*)(pI + kk * 32);
      const short8 bO = *(const short8*)(pO + kk * 32);
      const short8 bU = *(const short8*)(pU + kk * 32);
      #pragma unroll
      for (int rt = 0; rt < 4; ++rt){
        const int row = rt * 16 + l15;
        const short8 a = *(const short8*)&At[swz(row, kk * 4 + quad)];
        acc[rt][0] = __builtin_amdgcn_mfma_f32_16x16x32_bf16(a, bF, acc[rt][0], 0, 0, 0);
        acc[rt][1] = __builtin_amdgcn_mfma_f32_16x16x32_bf16(a, bI, acc[rt][1], 0, 0, 0);
        acc[rt][2] = __builtin_amdgcn_mfma_f32_16x16x32_bf16(a, bO, acc[rt][2], 0, 0, 0);
        acc[rt][3] = __builtin_amdgcn_mfma_f32_16x16x32_bf16(a, bU, acc[rt][3], 0, 0, 0);
      }
    }

    const float bf = b2f(arena[A_UFB + colh]);
    const float bi = b2f(arena[A_BIOU + colh]);
    const float bo = b2f(arena[A_BIOU + 256 + colh]);
    const float bu = b2f(arena[A_BIOU + 512 + colh]);
    #pragma unroll
    for (int rt = 0; rt < 4; ++rt){
      const int rloc = rt * 16 + quad * 4;              // local child row, mult of 4
      const size_t crow = (size_t)(rowbase + rloc) * HB + colh;
      const float c0 = b2f(cch[crow]);
      const float c1 = b2f(cch[crow + HB]);
      const float c2 = b2f(cch[crow + 2 * HB]);
      const float c3 = b2f(cch[crow + 3 * HB]);
      const f32x4 dF = acc[rt][0], dI = acc[rt][1], dO = acc[rt][2], dU = acc[rt][3];
      const int p0 = pbase + (rloc >> 1);
      {
        const float ca = fsig(dF[0] + bf) * c0 + fsig(dF[1] + bf) * c1;
        const float ig = fsig(dI[0] + dI[1] + bi);
        const float og = fsig(dO[0] + dO[1] + bo);
        const float ug = ftanh(dU[0] + dU[1] + bu);
        const float cv = ig * ug + ca;
        const float hv = og * ftanh(cv);
        const size_t o = (size_t)p0 * HB + colh;
        hout[o] = f2b(hv); cout[o] = f2b(cv);
      }
      {
        const float ca = fsig(dF[2] + bf) * c2 + fsig(dF[3] + bf) * c3;
        const float ig = fsig(dI[2] + dI[3] + bi);
        const float og = fsig(dO[2] + dO[3] + bo);
        const float ug = ftanh(dU[2] + dU[3] + bu);
        const float cv = ig * ug + ca;
        const float hv = og * ftanh(cv);
        const size_t o = (size_t)(p0 + 1) * HB + colh;
        hout[o] = f2b(hv); cout[o] = f2b(cv);
      }
    }
  }
}

// ---------------- final reduction -> x2 (fp32, B x 544) ----------------------------------
__global__ __launch_bounds__(1024)
void reduce_kernel(const short* __restrict__ hall, const short* __restrict__ arena,
                   float* __restrict__ x2)
{
  __shared__ float sums[32][256];
  const int b = blockIdx.x, t = threadIdx.x;
  const int g = t >> 5, cb = (t & 31) * 8;
  float s[8];
  #pragma unroll
  for (int e = 0; e < 8; ++e) s[e] = 0.f;
  size_t base = 0;
  for (int d = 0; d <= 8; ++d){
    const int m = 1 << d;
    for (int j = g; j < m; j += 32){
      const short8 v = *(const short8*)(hall + base + (size_t)(b * m + j) * HB + cb);
      #pragma unroll
      for (int e = 0; e < 8; ++e) s[e] += b2f(v[e]);
    }
    base += (size_t)256 * m * HB;
  }
  #pragma unroll
  for (int e = 0; e < 8; ++e) sums[g][cb + e] = s[e];
  __syncthreads();
  if (t < 256){
    float tot = 0.f;
    #pragma unroll
    for (int gg = 0; gg < 32; ++gg) tot += sums[gg][t];
    const float head = b2f(hall[(size_t)b * HB + t]);
    const float last = b2f(hall[(size_t)BASE8 + ((size_t)b * 256 + 255) * HB + t]);
    x2[(size_t)b * 544 + t]       = head;
    x2[(size_t)b * 544 + 256 + t] = (tot - head - last) * (1.f / 509.f);
  } else if (t < 288){
    x2[(size_t)b * 544 + 512 + (t - 256)] = b2f(arena[A_EMO + b * 32 + (t - 256)]);
  }
}

// ---------------- head MLP: 544 -> 128 -> 64 -> 4 ----------------------------------------
__global__ __launch_bounds__(256)
void head_kernel(const float* __restrict__ x2, const short* __restrict__ arena,
                 const int* __restrict__ flag, void* __restrict__ outv)
{
  __shared__ float sx[544];
  __shared__ float sy1[128];
  __shared__ float sy2[64];
  const int b = blockIdx.x, t = threadIdx.x;
  for (int i = t; i < 544; i += 256) sx[i] = x2[(size_t)b * 544 + i];
  __syncthreads();
  if (t < 128){
    float a = b2f(arena[A_BIN + t]);
    const short* wr = arena + A_WIN + (size_t)t * 544;
    for (int k = 0; k < 544; ++k) a += sx[k] * b2f(wr[k]);
    sy1[t] = fmaxf(a, 0.f);
  }
  __syncthreads();
  if (t < 64){
    float a = b2f(arena[A_BMID + t]);
    const short* wr = arena + A_WMID + (size_t)t * 128;
    for (int k = 0; k < 128; ++k) a += sy1[k] * b2f(wr[k]);
    sy2[t] = fmaxf(a, 0.f);
  }
  __syncthreads();
  if (t < 4){
    float a = b2f(arena[A_BOUT + t]);
    const short* wr = arena + A_WOUT + (size_t)t * 64;
    for (int k = 0; k < 64; ++k) a += sy2[k] * b2f(wr[k]);
    const float sg = fsig(a);
    if (*flag) ((float*)outv)[(size_t)b * 4 + t] = sg;
    else       ((short*)outv)[(size_t)b * 4 + t] = f2b(sg);
  }
}

extern "C" void kernel_launch(void* const* d_in, const int* in_sizes, int n_in,
                              void* d_out, int out_size, void* d_ws, size_t ws_size,
                              hipStream_t stream)
{
  (void)in_sizes; (void)n_in; (void)out_size; (void)ws_size;
  const void* X    = d_in[0];
  const void* emo  = d_in[3];
  const void* Wiou = d_in[4];
  const void* Uiou = d_in[5];
  const void* biou = d_in[6];
  const void* Ufw  = d_in[7];
  const void* Ufb  = d_in[8];
  const void* Win  = d_in[9];
  const void* bin  = d_in[10];
  const void* Wmid = d_in[11];
  const void* bmid = d_in[12];
  const void* Wout = d_in[13];
  const void* bout = d_in[14];

  char* ws = (char*)d_ws;
  short* h_all = (short*)ws;
  short* cbufA = (short*)(ws + 66977792);
  short* cbufB = (short*)(ws + 100532224);
  short* arena = (short*)(ws + 117309440);
  int*   flag  = (int*)  (ws + 118401928);
  float* x2    = (float*)(ws + 118401936);

  dim3 blk(256);

  probe_kernel<<<dim3(1), blk, 0, stream>>>(X, flag);
  conv_kernel<<<dim3((A_TOT + 255) / 256), blk, 0, stream>>>(
      Wiou, Uiou, biou, Ufw, Ufb, Win, bin, Wmid, bmid, Wout, bout, emo, arena, flag);

  leaf_kernel<<<dim3(1024), blk, 0, stream>>>(X, arena, flag, h_all, cbufA);

  for (int d = 7; d >= 0; --d){
    const int m = 1 << d;
    const size_t base_p  = (size_t)256 * (m - 1) * HB;
    const size_t base_ch = (size_t)256 * (2 * m - 1) * HB;
    short* csrc = ((d + 1) & 1) ? cbufB : cbufA;
    short* cdst = (d & 1) ? cbufB : cbufA;
    const int childrows = 512 * m;
    const int spb = (childrows >= 16384) ? 4 : ((childrows >= 8192) ? 2 : 1);
    dim3 grid(childrows / 64, 4 / spb);
    level_kernel<<<grid, blk, 0, stream>>>(h_all + base_ch, csrc, arena,
                                           h_all + base_p, cdst, spb);
  }

  reduce_kernel<<<dim3(256), dim3(1024), 0, stream>>>(h_all, arena, x2);
  head_kernel<<<dim3(256), blk, 0, stream>>>(x2, arena, flag, d_out);
}

// Round 8
// 810.928 us; speedup vs baseline: 1.1528x; 1.1528x over previous
//
#include <hip/hip_runtime.h>

// DeepTreeLSTM on MI355X (gfx950). Inputs fp32 (verified R3); dtype probe kept.
// Tree: 511 nodes, level d has 2^d nodes. h level-major: base_d = 256*(2^d-1)*256.
//
// R7 post-mortem: acc64+staging ~160 regs > 128 cap at 4 waves/SIMD -> spill
// (FETCH 342MB). R8: wave tile acc[2][4]=32 f32 (~85 regs) + 32KB LDS tile ->
// true 4 blocks/CU. Levels d=3..0 fused into one per-batch tail kernel.
//
// Workspace (<= ~119 MB):
//   h_all  bf16 [0,           66,977,792)
//   cbufA  bf16 [66,977,792, 100,532,224)   c for even levels (8,6,4)
//   cbufB  bf16 [100,532,224,117,309,440)   c for odd levels (7,5)
//   arena  bf16 [117,309,440,118,401,928)   converted weights/biases/emo
//   flag   int  [118,401,928,118,401,932)
//   x2     fp32 [118,401,936,118,958,992)

typedef __attribute__((ext_vector_type(8))) short short8;
typedef __attribute__((ext_vector_type(4))) float f32x4;

#define HB 256
#define BASE8 16711680   // 256*255*256
#define BASE4 983040     // 256*15*256

#define A_WIOU 0
#define A_UIOU 196608
#define A_BIOU 393216
#define A_UFW  393984
#define A_UFB  459520
#define A_WIN  459776
#define A_BIN  529408
#define A_WMID 529536
#define A_BMID 537728
#define A_WOUT 537792
#define A_BOUT 538048
#define A_EMO  538052
#define A_TOT  546244

__device__ __forceinline__ float b2f(short s){
  union { unsigned u; float f; } v; v.u = ((unsigned)(unsigned short)s) << 16; return v.f;
}
__device__ __forceinline__ short f2b(float f){
  union { float f; unsigned u; } v; v.f = f;
  unsigned r = v.u + 0x7fffu + ((v.u >> 16) & 1u);   // RNE
  return (short)(unsigned short)(r >> 16);
}
__device__ __forceinline__ float fsig(float x){ return 1.f / (1.f + __expf(-x)); }
__device__ __forceinline__ float ftanh(float x){
  x = fminf(fmaxf(x, -10.f), 10.f);
  float e = __expf(2.f * x);
  return (e - 1.f) / (e + 1.f);
}

// LDS A-tile: 64 rows x 256 k, XOR-swizzled 8-short groups (32 KB).
__device__ __forceinline__ int swz(int row, int g){   // g = k>>3
  return row * 256 + (((g ^ (row & 31)) & 31) << 3);
}

// ---------------- dtype probe ------------------------------------------------------------
__global__ __launch_bounds__(256)
void probe_kernel(const void* __restrict__ X, int* __restrict__ flag)
{
  __shared__ int sh[256];
  const int t = threadIdx.x;
  const unsigned short* p = (const unsigned short*)X;
  int cnt = 0;
  #pragma unroll
  for (int k = 0; k < 16; ++k){
    unsigned e = (p[t * 16 + k] >> 7) & 0xFFu;
    cnt += (e >= 0xC0u);
  }
  sh[t] = cnt; __syncthreads();
  for (int s = 128; s > 0; s >>= 1){ if (t < s) sh[t] += sh[t + s]; __syncthreads(); }
  if (t == 0) *flag = (sh[0] >= 16) ? 1 : 0;
}

// ---------------- convert params into bf16 arena -----------------------------------------
__global__ __launch_bounds__(256)
void conv_kernel(const void* s0, const void* s1, const void* s2, const void* s3,
                 const void* s4, const void* s5, const void* s6, const void* s7,
                 const void* s8, const void* s9, const void* s10, const void* s11,
                 short* __restrict__ arena, const int* __restrict__ flag)
{
  const int i = blockIdx.x * 256 + threadIdx.x;
  if (i >= A_TOT) return;
  const int bounds[13] = {A_WIOU, A_UIOU, A_BIOU, A_UFW, A_UFB, A_WIN, A_BIN,
                          A_WMID, A_BMID, A_WOUT, A_BOUT, A_EMO, A_TOT};
  const void* sp[12] = {s0,s1,s2,s3,s4,s5,s6,s7,s8,s9,s10,s11};
  int seg = 0;
  #pragma unroll
  for (int k = 1; k < 12; ++k) if (i >= bounds[k]) seg = k;
  const int j = i - bounds[seg];
  const float v = (*flag) ? ((const float*)sp[seg])[j] : b2f(((const short*)sp[seg])[j]);
  arena[i] = f2b(v);
}

// ---------------- leaf: 64-row tile, wave = 32 rows x 16 cols x 3 gates ------------------
// grid (1024), block 256 (2 row-halves x 2 col-halves), 8 col-slices of 32.
__global__ __launch_bounds__(256, 4)
void leaf_kernel(const void* __restrict__ X, const short* __restrict__ arena,
                 const int* __restrict__ flag,
                 short* __restrict__ hall, short* __restrict__ cout)
{
  __shared__ short At[16384];
  const int t = threadIdx.x, lane = t & 63, w = t >> 6;
  const int l15 = lane & 15, quad = lane >> 4;
  const int rh = w >> 1, cl = w & 1;
  const int rowbase = 64 * blockIdx.x;
  const size_t grow0 = ((size_t)(rowbase >> 8) * 511 + 255 + (rowbase & 255)) * HB;
  const bool isf = (*flag) != 0;

  #pragma unroll
  for (int i = 0; i < 8; ++i){
    const int gi = i * 256 + t;
    const int row = gi >> 5, g = gi & 31;
    short8 v;
    if (isf){
      const float* p = (const float*)X + grow0 + (size_t)row * HB + g * 8;
      const float4 u = *(const float4*)p;
      const float4 q = *(const float4*)(p + 4);
      v[0]=f2b(u.x); v[1]=f2b(u.y); v[2]=f2b(u.z); v[3]=f2b(u.w);
      v[4]=f2b(q.x); v[5]=f2b(q.y); v[6]=f2b(q.z); v[7]=f2b(q.w);
    } else {
      v = *(const short8*)((const short*)X + grow0 + (size_t)row * HB + g * 8);
    }
    *(short8*)&At[swz(row, g)] = v;
  }
  __syncthreads();

  #pragma unroll
  for (int s = 0; s < 8; ++s){
    const int colh = s * 32 + cl * 16 + l15;
    const short* pI = arena + A_WIOU + (size_t)colh * HB + quad * 8;
    const short* pO = pI + 65536;
    const short* pU = pI + 131072;

    f32x4 acc[2][3];
    #pragma unroll
    for (int rt = 0; rt < 2; ++rt)
      #pragma unroll
      for (int g = 0; g < 3; ++g) acc[rt][g] = (f32x4){0.f,0.f,0.f,0.f};

    #pragma unroll
    for (int kk = 0; kk < 8; ++kk){
      const short8 bI = *(const short8*)(pI + kk * 32);
      const short8 bO = *(const short8*)(pO + kk * 32);
      const short8 bU = *(const short8*)(pU + kk * 32);
      #pragma unroll
      for (int rt = 0; rt < 2; ++rt){
        const int row = rh * 32 + rt * 16 + l15;
        const short8 a = *(const short8*)&At[swz(row, kk * 4 + quad)];
        acc[rt][0] = __builtin_amdgcn_mfma_f32_16x16x32_bf16(a, bI, acc[rt][0], 0, 0, 0);
        acc[rt][1] = __builtin_amdgcn_mfma_f32_16x16x32_bf16(a, bO, acc[rt][1], 0, 0, 0);
        acc[rt][2] = __builtin_amdgcn_mfma_f32_16x16x32_bf16(a, bU, acc[rt][2], 0, 0, 0);
      }
    }

    const float bi = b2f(arena[A_BIOU + colh]);
    const float bo = b2f(arena[A_BIOU + 256 + colh]);
    const float bu = b2f(arena[A_BIOU + 512 + colh]);
    #pragma unroll
    for (int rt = 0; rt < 2; ++rt){
      const f32x4 vi = acc[rt][0], vo = acc[rt][1], vu = acc[rt][2];
      #pragma unroll
      for (int r = 0; r < 4; ++r){
        const int row = rowbase + rh * 32 + rt * 16 + quad * 4 + r;
        const float ig = fsig(vi[r] + bi);
        const float og = fsig(vo[r] + bo);
        const float ug = ftanh(vu[r] + bu);
        const float cv = ig * ug;                       // c_in = 0
        const float hv = og * ftanh(cv);
        const size_t o = (size_t)row * HB + colh;
        hall[BASE8 + o] = f2b(hv);
        cout[o] = f2b(cv);
      }
    }
  }
}

// ---------------- level (d=7..4): 64-row tile, wave = 32 rows x 16 cols x {F,I,O,U} ------
// grid (childrows/64, 8/spb), block 256. Col slices [blockIdx.y*spb, +spb) of 32 cols.
__global__ __launch_bounds__(256, 4)
void level_kernel(const short* __restrict__ hch, const short* __restrict__ cch,
                  const short* __restrict__ arena,
                  short* __restrict__ hout, short* __restrict__ cout, int spb)
{
  __shared__ short At[16384];
  const int t = threadIdx.x, lane = t & 63, w = t >> 6;
  const int l15 = lane & 15, quad = lane >> 4;
  const int rh = w >> 1, cl = w & 1;
  const int rowbase = 64 * blockIdx.x;                  // child rows
  const int pbase   = 32 * blockIdx.x;                  // parent rows

  #pragma unroll
  for (int i = 0; i < 8; ++i){
    const int gi = i * 256 + t;
    const int row = gi >> 5, g = gi & 31;
    *(short8*)&At[swz(row, g)] =
        *(const short8*)(hch + (size_t)(rowbase + row) * HB + g * 8);
  }
  __syncthreads();

  const int s0 = blockIdx.y * spb;
  for (int s = s0; s < s0 + spb; ++s){
    const int colh = s * 32 + cl * 16 + l15;
    const short* pF = arena + A_UFW  + (size_t)colh * HB + quad * 8;
    const short* pI = arena + A_UIOU + (size_t)colh * HB + quad * 8;
    const short* pO = pI + 65536;
    const short* pU = pI + 131072;

    f32x4 acc[2][4];
    #pragma unroll
    for (int rt = 0; rt < 2; ++rt)
      #pragma unroll
      for (int g = 0; g < 4; ++g) acc[rt][g] = (f32x4){0.f,0.f,0.f,0.f};

    #pragma unroll
    for (int kk = 0; kk < 8; ++kk){
      const short8 bF = *(const short8*)(pF + kk * 32);
      const short8 bI = *(const short8*)(pI + kk * 32);
      const short8 bO = *(const short8*)(pO + kk * 32);
      const short8 bU = *(const short8*)(pU + kk * 32);
      #pragma unroll
      for (int rt = 0; rt < 2; ++rt){
        const int row = rh * 32 + rt * 16 + l15;
        const short8 a = *(const short8*)&At[swz(row, kk * 4 + quad)];
        acc[rt][0] = __builtin_amdgcn_mfma_f32_16x16x32_bf16(a, bF, acc[rt][0], 0, 0, 0);
        acc[rt][1] = __builtin_amdgcn_mfma_f32_16x16x32_bf16(a, bI, acc[rt][1], 0, 0, 0);
        acc[rt][2] = __builtin_amdgcn_mfma_f32_16x16x32_bf16(a, bO, acc[rt][2], 0, 0, 0);
        acc[rt][3] = __builtin_amdgcn_mfma_f32_16x16x32_bf16(a, bU, acc[rt][3], 0, 0, 0);
      }
    }

    const float bf = b2f(arena[A_UFB + colh]);
    const float bi = b2f(arena[A_BIOU + colh]);
    const float bo = b2f(arena[A_BIOU + 256 + colh]);
    const float bu = b2f(arena[A_BIOU + 512 + colh]);
    #pragma unroll
    for (int rt = 0; rt < 2; ++rt){
      const int rloc = rh * 32 + rt * 16 + quad * 4;    // local child row, mult of 4
      const size_t crow = (size_t)(rowbase + rloc) * HB + colh;
      const float c0 = b2f(cch[crow]);
      const float c1 = b2f(cch[crow + HB]);
      const float c2 = b2f(cch[crow + 2 * HB]);
      const float c3 = b2f(cch[crow + 3 * HB]);
      const f32x4 dF = acc[rt][0], dI = acc[rt][1], dO = acc[rt][2], dU = acc[rt][3];
      const int p0 = pbase + (rloc >> 1);
      {
        const float ca = fsig(dF[0] + bf) * c0 + fsig(dF[1] + bf) * c1;
        const float ig = fsig(dI[0] + dI[1] + bi);
        const float og = fsig(dO[0] + dO[1] + bo);
        const float ug = ftanh(dU[0] + dU[1] + bu);
        const float cv = ig * ug + ca;
        const float hv = og * ftanh(cv);
        const size_t o = (size_t)p0 * HB + colh;
        hout[o] = f2b(hv); cout[o] = f2b(cv);
      }
      {
        const float ca = fsig(dF[2] + bf) * c2 + fsig(dF[3] + bf) * c3;
        const float ig = fsig(dI[2] + dI[3] + bi);
        const float og = fsig(dO[2] + dO[3] + bo);
        const float ug = ftanh(dU[2] + dU[3] + bu);
        const float cv = ig * ug + ca;
        const float hv = og * ftanh(cv);
        const size_t o = (size_t)(p0 + 1) * HB + colh;
        hout[o] = f2b(hv); cout[o] = f2b(cv);
      }
    }
  }
}

// ---------------- tail: levels d=3..0, one block per batch element -----------------------
// Stages level-4 h,c (16 rows) in LDS; each sub-level is a 16-row GEMM over 4 col
// passes (wave w -> cols pass*64 + w*16). h of each level written to h_all; h,c
// ping-pong in LDS for the next level. Pad rows (>= nch) compute garbage that is
// never stored.
__global__ __launch_bounds__(256)
void tail_kernel(short* __restrict__ hall, const short* __restrict__ c4,
                 const short* __restrict__ arena)
{
  __shared__ short hb[2][16 * 264];
  __shared__ short cb[2][16 * 264];
  const int t = threadIdx.x, lane = t & 63, w = t >> 6;
  const int l15 = lane & 15, quad = lane >> 4;
  const int b = blockIdx.x;

  // stage level-4 children: 16 rows x 256
  {
    const int row = t >> 4, cg = (t & 15) * 16;
    const short* hsrc = hall + BASE4 + (size_t)(b * 16 + row) * HB + cg;
    const short* csrc = c4 + (size_t)(b * 16 + row) * HB + cg;
    *(short8*)&hb[0][row * 264 + cg]     = *(const short8*)hsrc;
    *(short8*)&hb[0][row * 264 + cg + 8] = *(const short8*)(hsrc + 8);
    *(short8*)&cb[0][row * 264 + cg]     = *(const short8*)csrc;
    *(short8*)&cb[0][row * 264 + cg + 8] = *(const short8*)(csrc + 8);
  }
  __syncthreads();

  #pragma unroll
  for (int d = 3; d >= 0; --d){
    const int m = 1 << d;
    const int cur = (3 - d) & 1, nxt = cur ^ 1;
    const size_t base_d = (size_t)256 * (m - 1) * HB;

    for (int pass = 0; pass < 4; ++pass){
      const int colh = pass * 64 + w * 16 + l15;
      const short* pF = arena + A_UFW  + (size_t)colh * HB + quad * 8;
      const short* pI = arena + A_UIOU + (size_t)colh * HB + quad * 8;
      const short* pO = pI + 65536;
      const short* pU = pI + 131072;

      f32x4 aF = (f32x4){0.f,0.f,0.f,0.f}, aI = aF, aO = aF, aU = aF;
      #pragma unroll
      for (int kk = 0; kk < 8; ++kk){
        const short8 a = *(const short8*)&hb[cur][l15 * 264 + kk * 32 + quad * 8];
        aF = __builtin_amdgcn_mfma_f32_16x16x32_bf16(a, *(const short8*)(pF + kk*32), aF, 0,0,0);
        aI = __builtin_amdgcn_mfma_f32_16x16x32_bf16(a, *(const short8*)(pI + kk*32), aI, 0,0,0);
        aO = __builtin_amdgcn_mfma_f32_16x16x32_bf16(a, *(const short8*)(pO + kk*32), aO, 0,0,0);
        aU = __builtin_amdgcn_mfma_f32_16x16x32_bf16(a, *(const short8*)(pU + kk*32), aU, 0,0,0);
      }

      const float bfb = b2f(arena[A_UFB + colh]);
      const float bi = b2f(arena[A_BIOU + colh]);
      const float bo = b2f(arena[A_BIOU + 256 + colh]);
      const float bu = b2f(arena[A_BIOU + 512 + colh]);
      const int rbase = quad * 4;                       // child rows rbase..rbase+3
      #pragma unroll
      for (int pr = 0; pr < 2; ++pr){                   // parent = quad*2 + pr
        const int p = quad * 2 + pr;
        if (p < m){
          const int r0 = rbase + pr * 2;
          const float c0 = b2f(cb[cur][r0 * 264 + colh]);
          const float c1 = b2f(cb[cur][(r0 + 1) * 264 + colh]);
          const float ca = fsig(aF[pr*2] + bfb) * c0 + fsig(aF[pr*2+1] + bfb) * c1;
          const float ig = fsig(aI[pr*2] + aI[pr*2+1] + bi);
          const float og = fsig(aO[pr*2] + aO[pr*2+1] + bo);
          const float ug = ftanh(aU[pr*2] + aU[pr*2+1] + bu);
          const float cv = ig * ug + ca;
          const float hv = og * ftanh(cv);
          const short hvb = f2b(hv);
          hall[base_d + (size_t)(b * m + p) * HB + colh] = hvb;
          hb[nxt][p * 264 + colh] = hvb;
          cb[nxt][p * 264 + colh] = f2b(cv);
        }
      }
    }
    __syncthreads();
  }
}

// ---------------- final reduction -> x2 (fp32, B x 544) ----------------------------------
__global__ __launch_bounds__(1024)
void reduce_kernel(const short* __restrict__ hall, const short* __restrict__ arena,
                   float* __restrict__ x2)
{
  __shared__ float sums[32][256];
  const int b = blockIdx.x, t = threadIdx.x;
  const int g = t >> 5, cb = (t & 31) * 8;
  float s[8];
  #pragma unroll
  for (int e = 0; e < 8; ++e) s[e] = 0.f;
  size_t base = 0;
  for (int d = 0; d <= 8; ++d){
    const int m = 1 << d;
    for (int j = g; j < m; j += 32){
      const short8 v = *(const short8*)(hall + base + (size_t)(b * m + j) * HB + cb);
      #pragma unroll
      for (int e = 0; e < 8; ++e) s[e] += b2f(v[e]);
    }
    base += (size_t)256 * m * HB;
  }
  #pragma unroll
  for (int e = 0; e < 8; ++e) sums[g][cb + e] = s[e];
  __syncthreads();
  if (t < 256){
    float tot = 0.f;
    #pragma unroll
    for (int gg = 0; gg < 32; ++gg) tot += sums[gg][t];
    const float head = b2f(hall[(size_t)b * HB + t]);
    const float last = b2f(hall[(size_t)BASE8 + ((size_t)b * 256 + 255) * HB + t]);
    x2[(size_t)b * 544 + t]       = head;
    x2[(size_t)b * 544 + 256 + t] = (tot - head - last) * (1.f / 509.f);
  } else if (t < 288){
    x2[(size_t)b * 544 + 512 + (t - 256)] = b2f(arena[A_EMO + b * 32 + (t - 256)]);
  }
}

// ---------------- head MLP: 544 -> 128 -> 64 -> 4 ----------------------------------------
__global__ __launch_bounds__(256)
void head_kernel(const float* __restrict__ x2, const short* __restrict__ arena,
                 const int* __restrict__ flag, void* __restrict__ outv)
{
  __shared__ float sx[544];
  __shared__ float sy1[128];
  __shared__ float sy2[64];
  const int b = blockIdx.x, t = threadIdx.x;
  for (int i = t; i < 544; i += 256) sx[i] = x2[(size_t)b * 544 + i];
  __syncthreads();
  if (t < 128){
    float a = b2f(arena[A_BIN + t]);
    const short* wr = arena + A_WIN + (size_t)t * 544;
    for (int k = 0; k < 544; ++k) a += sx[k] * b2f(wr[k]);
    sy1[t] = fmaxf(a, 0.f);
  }
  __syncthreads();
  if (t < 64){
    float a = b2f(arena[A_BMID + t]);
    const short* wr = arena + A_WMID + (size_t)t * 128;
    for (int k = 0; k < 128; ++k) a += sy1[k] * b2f(wr[k]);
    sy2[t] = fmaxf(a, 0.f);
  }
  __syncthreads();
  if (t < 4){
    float a = b2f(arena[A_BOUT + t]);
    const short* wr = arena + A_WOUT + (size_t)t * 64;
    for (int k = 0; k < 64; ++k) a += sy2[k] * b2f(wr[k]);
    const float sg = fsig(a);
    if (*flag) ((float*)outv)[(size_t)b * 4 + t] = sg;
    else       ((short*)outv)[(size_t)b * 4 + t] = f2b(sg);
  }
}

extern "C" void kernel_launch(void* const* d_in, const int* in_sizes, int n_in,
                              void* d_out, int out_size, void* d_ws, size_t ws_size,
                              hipStream_t stream)
{
  (void)in_sizes; (void)n_in; (void)out_size; (void)ws_size;
  const void* X    = d_in[0];
  const void* emo  = d_in[3];
  const void* Wiou = d_in[4];
  const void* Uiou = d_in[5];
  const void* biou = d_in[6];
  const void* Ufw  = d_in[7];
  const void* Ufb  = d_in[8];
  const void* Win  = d_in[9];
  const void* bin  = d_in[10];
  const void* Wmid = d_in[11];
  const void* bmid = d_in[12];
  const void* Wout = d_in[13];
  const void* bout = d_in[14];

  char* ws = (char*)d_ws;
  short* h_all = (short*)ws;
  short* cbufA = (short*)(ws + 66977792);
  short* cbufB = (short*)(ws + 100532224);
  short* arena = (short*)(ws + 117309440);
  int*   flag  = (int*)  (ws + 118401928);
  float* x2    = (float*)(ws + 118401936);

  dim3 blk(256);

  probe_kernel<<<dim3(1), blk, 0, stream>>>(X, flag);
  conv_kernel<<<dim3((A_TOT + 255) / 256), blk, 0, stream>>>(
      Wiou, Uiou, biou, Ufw, Ufb, Win, bin, Wmid, bmid, Wout, bout, emo, arena, flag);

  leaf_kernel<<<dim3(1024), blk, 0, stream>>>(X, arena, flag, h_all, cbufA);

  for (int d = 7; d >= 4; --d){
    const int m = 1 << d;
    const size_t base_p  = (size_t)256 * (m - 1) * HB;
    const size_t base_ch = (size_t)256 * (2 * m - 1) * HB;
    short* csrc = ((d + 1) & 1) ? cbufB : cbufA;
    short* cdst = (d & 1) ? cbufB : cbufA;
    const int childrows = 512 * m;
    const int ycnt = (childrows >= 16384) ? 1 : 2;      // keep >= 256 blocks
    level_kernel<<<dim3(childrows / 64, ycnt), blk, 0, stream>>>(
        h_all + base_ch, csrc, arena, h_all + base_p, cdst, 8 / ycnt);
  }

  // levels 3..0 fused; level-4 c lives in cbufA (d=4 even)
  tail_kernel<<<dim3(256), blk, 0, stream>>>(h_all, cbufA, arena);

  reduce_kernel<<<dim3(256), dim3(1024), 0, stream>>>(h_all, arena, x2);
  head_kernel<<<dim3(256), blk, 0, stream>>>(x2, arena, flag, d_out);
}

// Round 9
// 683.643 us; speedup vs baseline: 1.3675x; 1.1862x over previous
//
#include <hip/hip_runtime.h>

// DeepTreeLSTM on MI355X (gfx950). Inputs fp32 (verified R3); dtype probe kept.
// Tree: 511 nodes, level d has 2^d nodes. h level-major: base_d = 256*(2^d-1)*256.
//
// R8 lesson: acc[4][4] @ 2 blocks/CU (R6 config, 101us for d=7) beats acc[2][4]
// @ 4 blocks/CU (151us) — register-rich waves win. This round: R6 config for the
// two big GEMMs (leaf, d=7), and levels d=6..0 + reduce + head fused into ONE
// per-batch kernel (256 blocks, LDS-resident subtree recursion).
//
// Workspace:
//   h_all  bf16 [0,           66,977,792)    (only levels 7,8 written now)
//   cbufA  bf16 [66,977,792, 100,532,224)   c8 (leaf out)
//   cbufB  bf16 [100,532,224,117,309,440)   c7 (level7 out)
//   arena  bf16 [117,309,440,118,401,928)   converted weights/biases/emo
//   flag   int  [118,401,928,118,401,932)

typedef __attribute__((ext_vector_type(8))) short short8;
typedef __attribute__((ext_vector_type(4))) float f32x4;

#define HB 256
#define BASE8 16711680   // 256*255*256
#define BASE7 8323072    // 256*127*256

#define A_WIOU 0
#define A_UIOU 196608
#define A_BIOU 393216
#define A_UFW  393984
#define A_UFB  459520
#define A_WIN  459776
#define A_BIN  529408
#define A_WMID 529536
#define A_BMID 537728
#define A_WOUT 537792
#define A_BOUT 538048
#define A_EMO  538052
#define A_TOT  546244

__device__ __forceinline__ float b2f(short s){
  union { unsigned u; float f; } v; v.u = ((unsigned)(unsigned short)s) << 16; return v.f;
}
__device__ __forceinline__ short f2b(float f){
  union { float f; unsigned u; } v; v.f = f;
  unsigned r = v.u + 0x7fffu + ((v.u >> 16) & 1u);   // RNE
  return (short)(unsigned short)(r >> 16);
}
__device__ __forceinline__ float fsig(float x){ return 1.f / (1.f + __expf(-x)); }
__device__ __forceinline__ float ftanh(float x){
  x = fminf(fmaxf(x, -10.f), 10.f);
  float e = __expf(2.f * x);
  return (e - 1.f) / (e + 1.f);
}

// LDS A-tile (leaf/level7): 128 rows x 256 k, XOR-swizzled 8-short groups (64 KB).
__device__ __forceinline__ int swz(int row, int g){   // g = k>>3
  return row * 256 + (((g ^ (row & 31)) & 31) << 3);
}

// ---------------- dtype probe ------------------------------------------------------------
__global__ __launch_bounds__(256)
void probe_kernel(const void* __restrict__ X, int* __restrict__ flag)
{
  __shared__ int sh[256];
  const int t = threadIdx.x;
  const unsigned short* p = (const unsigned short*)X;
  int cnt = 0;
  #pragma unroll
  for (int k = 0; k < 16; ++k){
    unsigned e = (p[t * 16 + k] >> 7) & 0xFFu;
    cnt += (e >= 0xC0u);
  }
  sh[t] = cnt; __syncthreads();
  for (int s = 128; s > 0; s >>= 1){ if (t < s) sh[t] += sh[t + s]; __syncthreads(); }
  if (t == 0) *flag = (sh[0] >= 16) ? 1 : 0;
}

// ---------------- convert params into bf16 arena -----------------------------------------
__global__ __launch_bounds__(256)
void conv_kernel(const void* s0, const void* s1, const void* s2, const void* s3,
                 const void* s4, const void* s5, const void* s6, const void* s7,
                 const void* s8, const void* s9, const void* s10, const void* s11,
                 short* __restrict__ arena, const int* __restrict__ flag)
{
  const int i = blockIdx.x * 256 + threadIdx.x;
  if (i >= A_TOT) return;
  const int bounds[13] = {A_WIOU, A_UIOU, A_BIOU, A_UFW, A_UFB, A_WIN, A_BIN,
                          A_WMID, A_BMID, A_WOUT, A_BOUT, A_EMO, A_TOT};
  const void* sp[12] = {s0,s1,s2,s3,s4,s5,s6,s7,s8,s9,s10,s11};
  int seg = 0;
  #pragma unroll
  for (int k = 1; k < 12; ++k) if (i >= bounds[k]) seg = k;
  const int j = i - bounds[seg];
  const float v = (*flag) ? ((const float*)sp[seg])[j] : b2f(((const short*)sp[seg])[j]);
  arena[i] = f2b(v);
}

// ---------------- leaf (R6 config): 128-row tile, wave = 64 rows x 16 cols x 3 gates -----
// grid (512), block 256 (2 row-halves x 2 col-halves), 8 col-slices of 32.
__global__ __launch_bounds__(256, 2)
void leaf_kernel(const void* __restrict__ X, const short* __restrict__ arena,
                 const int* __restrict__ flag,
                 short* __restrict__ hall, short* __restrict__ cout)
{
  __shared__ short At[32768];
  const int t = threadIdx.x, lane = t & 63, w = t >> 6;
  const int l15 = lane & 15, quad = lane >> 4;
  const int rh = w >> 1, cl = w & 1;
  const int rowbase = 128 * blockIdx.x;
  const size_t grow0 = ((size_t)(rowbase >> 8) * 511 + 255 + (rowbase & 255)) * HB;
  const bool isf = (*flag) != 0;

  #pragma unroll
  for (int i = 0; i < 16; ++i){
    const int gi = i * 256 + t;
    const int row = gi >> 5, g = gi & 31;
    short8 v;
    if (isf){
      const float* p = (const float*)X + grow0 + (size_t)row * HB + g * 8;
      const float4 u = *(const float4*)p;
      const float4 q = *(const float4*)(p + 4);
      v[0]=f2b(u.x); v[1]=f2b(u.y); v[2]=f2b(u.z); v[3]=f2b(u.w);
      v[4]=f2b(q.x); v[5]=f2b(q.y); v[6]=f2b(q.z); v[7]=f2b(q.w);
    } else {
      v = *(const short8*)((const short*)X + grow0 + (size_t)row * HB + g * 8);
    }
    *(short8*)&At[swz(row, g)] = v;
  }
  __syncthreads();

  #pragma unroll
  for (int s = 0; s < 8; ++s){
    const int colh = s * 32 + cl * 16 + l15;
    const short* pI = arena + A_WIOU + (size_t)colh * HB + quad * 8;
    const short* pO = pI + 65536;
    const short* pU = pI + 131072;

    f32x4 acc[4][3];
    #pragma unroll
    for (int rt = 0; rt < 4; ++rt)
      #pragma unroll
      for (int g = 0; g < 3; ++g) acc[rt][g] = (f32x4){0.f,0.f,0.f,0.f};

    #pragma unroll
    for (int kk = 0; kk < 8; ++kk){
      const short8 bI = *(const short8*)(pI + kk * 32);
      const short8 bO = *(const short8*)(pO + kk * 32);
      const short8 bU = *(const short8*)(pU + kk * 32);
      #pragma unroll
      for (int rt = 0; rt < 4; ++rt){
        const int row = rh * 64 + rt * 16 + l15;
        const short8 a = *(const short8*)&At[swz(row, kk * 4 + quad)];
        acc[rt][0] = __builtin_amdgcn_mfma_f32_16x16x32_bf16(a, bI, acc[rt][0], 0, 0, 0);
        acc[rt][1] = __builtin_amdgcn_mfma_f32_16x16x32_bf16(a, bO, acc[rt][1], 0, 0, 0);
        acc[rt][2] = __builtin_amdgcn_mfma_f32_16x16x32_bf16(a, bU, acc[rt][2], 0, 0, 0);
      }
    }

    const float bi = b2f(arena[A_BIOU + colh]);
    const float bo = b2f(arena[A_BIOU + 256 + colh]);
    const float bu = b2f(arena[A_BIOU + 512 + colh]);
    #pragma unroll
    for (int rt = 0; rt < 4; ++rt){
      const f32x4 vi = acc[rt][0], vo = acc[rt][1], vu = acc[rt][2];
      #pragma unroll
      for (int r = 0; r < 4; ++r){
        const int row = rowbase + rh * 64 + rt * 16 + quad * 4 + r;
        const float ig = fsig(vi[r] + bi);
        const float og = fsig(vo[r] + bo);
        const float ug = ftanh(vu[r] + bu);
        const float cv = ig * ug;                       // c_in = 0
        const float hv = og * ftanh(cv);
        const size_t o = (size_t)row * HB + colh;
        hall[BASE8 + o] = f2b(hv);
        cout[o] = f2b(cv);
      }
    }
  }
}

// ---------------- level 7 (R6 config): 128 child rows, wave = 64 rows x 16 cols x FIOU ---
// grid (512), block 256. 8 col-slices of 32; acc[4][4] = 64 f32/lane.
__global__ __launch_bounds__(256, 2)
void level7_kernel(const short* __restrict__ hch, const short* __restrict__ cch,
                   const short* __restrict__ arena,
                   short* __restrict__ hout, short* __restrict__ cout)
{
  __shared__ short At[32768];
  const int t = threadIdx.x, lane = t & 63, w = t >> 6;
  const int l15 = lane & 15, quad = lane >> 4;
  const int rh = w >> 1, cl = w & 1;
  const int rowbase = 128 * blockIdx.x;                 // child rows
  const int pbase   = 64 * blockIdx.x;                  // parent rows

  #pragma unroll
  for (int i = 0; i < 16; ++i){
    const int gi = i * 256 + t;
    const int row = gi >> 5, g = gi & 31;
    *(short8*)&At[swz(row, g)] =
        *(const short8*)(hch + (size_t)(rowbase + row) * HB + g * 8);
  }
  __syncthreads();

  #pragma unroll
  for (int s = 0; s < 8; ++s){
    const int colh = s * 32 + cl * 16 + l15;
    const short* pF = arena + A_UFW  + (size_t)colh * HB + quad * 8;
    const short* pI = arena + A_UIOU + (size_t)colh * HB + quad * 8;
    const short* pO = pI + 65536;
    const short* pU = pI + 131072;

    f32x4 acc[4][4];
    #pragma unroll
    for (int rt = 0; rt < 4; ++rt)
      #pragma unroll
      for (int g = 0; g < 4; ++g) acc[rt][g] = (f32x4){0.f,0.f,0.f,0.f};

    #pragma unroll
    for (int kk = 0; kk < 8; ++kk){
      const short8 bF = *(const short8*)(pF + kk * 32);
      const short8 bI = *(const short8*)(pI + kk * 32);
      const short8 bO = *(const short8*)(pO + kk * 32);
      const short8 bU = *(const short8*)(pU + kk * 32);
      #pragma unroll
      for (int rt = 0; rt < 4; ++rt){
        const int row = rh * 64 + rt * 16 + l15;
        const short8 a = *(const short8*)&At[swz(row, kk * 4 + quad)];
        acc[rt][0] = __builtin_amdgcn_mfma_f32_16x16x32_bf16(a, bF, acc[rt][0], 0, 0, 0);
        acc[rt][1] = __builtin_amdgcn_mfma_f32_16x16x32_bf16(a, bI, acc[rt][1], 0, 0, 0);
        acc[rt][2] = __builtin_amdgcn_mfma_f32_16x16x32_bf16(a, bO, acc[rt][2], 0, 0, 0);
        acc[rt][3] = __builtin_amdgcn_mfma_f32_16x16x32_bf16(a, bU, acc[rt][3], 0, 0, 0);
      }
    }

    const float bf = b2f(arena[A_UFB + colh]);
    const float bi = b2f(arena[A_BIOU + colh]);
    const float bo = b2f(arena[A_BIOU + 256 + colh]);
    const float bu = b2f(arena[A_BIOU + 512 + colh]);
    #pragma unroll
    for (int rt = 0; rt < 4; ++rt){
      const int rloc = rh * 64 + rt * 16 + quad * 4;
      const size_t crow = (size_t)(rowbase + rloc) * HB + colh;
      const float c0 = b2f(cch[crow]);
      const float c1 = b2f(cch[crow + HB]);
      const float c2 = b2f(cch[crow + 2 * HB]);
      const float c3 = b2f(cch[crow + 3 * HB]);
      const f32x4 dF = acc[rt][0], dI = acc[rt][1], dO = acc[rt][2], dU = acc[rt][3];
      const int p0 = pbase + (rloc >> 1);
      {
        const float ca = fsig(dF[0] + bf) * c0 + fsig(dF[1] + bf) * c1;
        const float ig = fsig(dI[0] + dI[1] + bi);
        const float og = fsig(dO[0] + dO[1] + bo);
        const float ug = ftanh(dU[0] + dU[1] + bu);
        const float cv = ig * ug + ca;
        const float hv = og * ftanh(cv);
        const size_t o = (size_t)p0 * HB + colh;
        hout[o] = f2b(hv); cout[o] = f2b(cv);
      }
      {
        const float ca = fsig(dF[2] + bf) * c2 + fsig(dF[3] + bf) * c3;
        const float ig = fsig(dI[2] + dI[3] + bi);
        const float og = fsig(dO[2] + dO[3] + bo);
        const float ug = ftanh(dU[2] + dU[3] + bu);
        const float cv = ig * ug + ca;
        const float hv = og * ftanh(cv);
        const size_t o = (size_t)(p0 + 1) * HB + colh;
        hout[o] = f2b(hv); cout[o] = f2b(cv);
      }
    }
  }
}

// ---------------- fused tail: levels d=6..0 + reduction + head MLP, 1 block/batch --------
// Dynamic LDS (156,032 B): HA 128x264, HBf 64x264, CBf 64x264, CAf 32x264 (bf16),
// scol[256], sx[544], sy1[128], sy2[64] (f32). h/c ping-pong: level d output ->
// (d odd ? A : B) region. c7 (children of d=6) streams from global.
__global__ __launch_bounds__(256)
void fused_kernel(const short* __restrict__ hall, const short* __restrict__ c7g,
                  const short* __restrict__ arena, const int* __restrict__ flag,
                  void* __restrict__ outv)
{
  extern __shared__ char smem[];
  short* HA  = (short*)smem;                 // 128*264 = 67584 B
  short* HBf = (short*)(smem + 67584);       // 64*264  = 33792 B
  short* CBf = (short*)(smem + 101376);      // 64*264  = 33792 B
  short* CAf = (short*)(smem + 135168);      // 32*264  = 16896 B
  float* scol = (float*)(smem + 152064);     // 1024 B
  float* sx   = (float*)(smem + 153088);     // 2176 B
  float* sy1  = (float*)(smem + 155264);     // 512 B
  float* sy2  = (float*)(smem + 155776);     // 256 B -> 156032

  const int t = threadIdx.x, lane = t & 63, w = t >> 6;
  const int l15 = lane & 15, quad = lane >> 4;
  const int b = blockIdx.x;

  scol[t] = 0.f;

  // stage h7 (128 rows x 256) into HA
  const short* h7 = hall + BASE7 + (size_t)b * 128 * HB;
  #pragma unroll
  for (int i = 0; i < 16; ++i){
    const int gi = i * 256 + t;
    const int row = gi >> 5, g = gi & 31;
    *(short8*)&HA[row * 264 + g * 8] = *(const short8*)(h7 + (size_t)row * HB + g * 8);
  }

  // stream-sum levels 8 and 7 into thread-private accumulator (thread t owns col t)
  const short* h8 = hall + BASE8 + (size_t)b * 256 * HB;
  float s = 0.f;
  #pragma unroll 4
  for (int j = 0; j < 256; ++j) s += b2f(h8[(size_t)j * HB + t]);
  #pragma unroll 4
  for (int j = 0; j < 128; ++j) s += b2f(h7[(size_t)j * HB + t]);
  scol[t] += s;
  const float lastv = b2f(h8[(size_t)255 * HB + t]);
  __syncthreads();

  // level recursion d = 6..0
  for (int d = 6; d >= 0; --d){
    const int n_ch = 2 << d;
    const int n_p  = 1 << d;
    const short* hin  = (d & 1) ? HBf : HA;   // input h region (level d+1 output)
    short*       hout = (d & 1) ? HA  : HBf;
    const short* cin  = (d & 1) ? CBf : CAf;  // input c region (d<6)
    short*       cl_  = (d & 1) ? CAf : CBf;  // output c region
    const bool cglob = (d == 6);
    const int nchunk = (n_ch + 31) >> 5;

    for (int pass = 0; pass < 4; ++pass){
      const int colh = pass * 64 + w * 16 + l15;
      const short* pF = arena + A_UFW  + (size_t)colh * HB + quad * 8;
      const short* pI = arena + A_UIOU + (size_t)colh * HB + quad * 8;
      const short* pO = pI + 65536;
      const short* pU = pI + 131072;
      const float bfb = b2f(arena[A_UFB + colh]);
      const float bi  = b2f(arena[A_BIOU + colh]);
      const float bo  = b2f(arena[A_BIOU + 256 + colh]);
      const float bu  = b2f(arena[A_BIOU + 512 + colh]);

      for (int rc = 0; rc < nchunk; ++rc){
        f32x4 acc[2][4];
        #pragma unroll
        for (int rt = 0; rt < 2; ++rt)
          #pragma unroll
          for (int g = 0; g < 4; ++g) acc[rt][g] = (f32x4){0.f,0.f,0.f,0.f};

        #pragma unroll
        for (int kk = 0; kk < 8; ++kk){
          const short8 vF = *(const short8*)(pF + kk * 32);
          const short8 vI = *(const short8*)(pI + kk * 32);
          const short8 vO = *(const short8*)(pO + kk * 32);
          const short8 vU = *(const short8*)(pU + kk * 32);
          #pragma unroll
          for (int rt = 0; rt < 2; ++rt){
            const int row = rc * 32 + rt * 16 + l15;
            const short8 a = *(const short8*)&hin[row * 264 + kk * 32 + quad * 8];
            acc[rt][0] = __builtin_amdgcn_mfma_f32_16x16x32_bf16(a, vF, acc[rt][0], 0, 0, 0);
            acc[rt][1] = __builtin_amdgcn_mfma_f32_16x16x32_bf16(a, vI, acc[rt][1], 0, 0, 0);
            acc[rt][2] = __builtin_amdgcn_mfma_f32_16x16x32_bf16(a, vO, acc[rt][2], 0, 0, 0);
            acc[rt][3] = __builtin_amdgcn_mfma_f32_16x16x32_bf16(a, vU, acc[rt][3], 0, 0, 0);
          }
        }

        #pragma unroll
        for (int rt = 0; rt < 2; ++rt){
          const int rloc = rc * 32 + rt * 16 + quad * 4;   // child row, mult of 4
          if (rloc < n_ch){
            float c0, c1, c2, c3;
            if (cglob){
              const size_t crow = (size_t)(b * 128 + rloc) * HB + colh;
              c0 = b2f(c7g[crow]);           c1 = b2f(c7g[crow + HB]);
              c2 = b2f(c7g[crow + 2 * HB]);  c3 = b2f(c7g[crow + 3 * HB]);
            } else {
              c0 = b2f(cin[(rloc    ) * 264 + colh]);
              c1 = b2f(cin[(rloc + 1) * 264 + colh]);
              c2 = b2f(cin[(rloc + 2) * 264 + colh]);
              c3 = b2f(cin[(rloc + 3) * 264 + colh]);
            }
            const f32x4 dF = acc[rt][0], dI = acc[rt][1], dO = acc[rt][2], dU = acc[rt][3];
            const int p0 = rloc >> 1;
            {
              const float ca = fsig(dF[0] + bfb) * c0 + fsig(dF[1] + bfb) * c1;
              const float ig = fsig(dI[0] + dI[1] + bi);
              const float og = fsig(dO[0] + dO[1] + bo);
              const float ug = ftanh(dU[0] + dU[1] + bu);
              const float cv = ig * ug + ca;
              const float hv = og * ftanh(cv);
              hout[p0 * 264 + colh] = f2b(hv);
              cl_[p0 * 264 + colh]  = f2b(cv);
            }
            if (rloc + 2 < n_ch){
              const float ca = fsig(dF[2] + bfb) * c2 + fsig(dF[3] + bfb) * c3;
              const float ig = fsig(dI[2] + dI[3] + bi);
              const float og = fsig(dO[2] + dO[3] + bo);
              const float ug = ftanh(dU[2] + dU[3] + bu);
              const float cv = ig * ug + ca;
              const float hv = og * ftanh(cv);
              hout[(p0 + 1) * 264 + colh] = f2b(hv);
              cl_[(p0 + 1) * 264 + colh]  = f2b(cv);
            }
          }
        }
      }
    }
    __syncthreads();
    // accumulate this level's h into scol (thread t owns col t)
    {
      float s2 = 0.f;
      for (int r = 0; r < n_p; ++r) s2 += b2f(hout[r * 264 + t]);
      scol[t] += s2;
    }
    __syncthreads();
  }

  // assemble x2 = [head | inner | emo]
  const float head = b2f(HBf[t]);                      // h0 -> B region, row 0
  sx[t]       = head;
  sx[256 + t] = (scol[t] - head - lastv) * (1.f / 509.f);
  if (t < 32) sx[512 + t] = b2f(arena[A_EMO + b * 32 + t]);
  __syncthreads();

  // head MLP 544 -> 128 -> 64 -> 4
  if (t < 128){
    float a = b2f(arena[A_BIN + t]);
    const short* wr = arena + A_WIN + (size_t)t * 544;
    for (int k = 0; k < 544; ++k) a += sx[k] * b2f(wr[k]);
    sy1[t] = fmaxf(a, 0.f);
  }
  __syncthreads();
  if (t < 64){
    float a = b2f(arena[A_BMID + t]);
    const short* wr = arena + A_WMID + (size_t)t * 128;
    for (int k = 0; k < 128; ++k) a += sy1[k] * b2f(wr[k]);
    sy2[t] = fmaxf(a, 0.f);
  }
  __syncthreads();
  if (t < 4){
    float a = b2f(arena[A_BOUT + t]);
    const short* wr = arena + A_WOUT + (size_t)t * 64;
    for (int k = 0; k < 64; ++k) a += sy2[k] * b2f(wr[k]);
    const float sg = fsig(a);
    if (*flag) ((float*)outv)[(size_t)b * 4 + t] = sg;
    else       ((short*)outv)[(size_t)b * 4 + t] = f2b(sg);
  }
}

extern "C" void kernel_launch(void* const* d_in, const int* in_sizes, int n_in,
                              void* d_out, int out_size, void* d_ws, size_t ws_size,
                              hipStream_t stream)
{
  (void)in_sizes; (void)n_in; (void)out_size; (void)ws_size;
  const void* X    = d_in[0];
  const void* emo  = d_in[3];
  const void* Wiou = d_in[4];
  const void* Uiou = d_in[5];
  const void* biou = d_in[6];
  const void* Ufw  = d_in[7];
  const void* Ufb  = d_in[8];
  const void* Win  = d_in[9];
  const void* bin  = d_in[10];
  const void* Wmid = d_in[11];
  const void* bmid = d_in[12];
  const void* Wout = d_in[13];
  const void* bout = d_in[14];

  char* ws = (char*)d_ws;
  short* h_all = (short*)ws;
  short* cbufA = (short*)(ws + 66977792);
  short* cbufB = (short*)(ws + 100532224);
  short* arena = (short*)(ws + 117309440);
  int*   flag  = (int*)  (ws + 118401928);

  const int FUSED_LDS = 156032;
  hipFuncSetAttribute((const void*)fused_kernel,
                      hipFuncAttributeMaxDynamicSharedMemorySize, FUSED_LDS);

  dim3 blk(256);

  probe_kernel<<<dim3(1), blk, 0, stream>>>(X, flag);
  conv_kernel<<<dim3((A_TOT + 255) / 256), blk, 0, stream>>>(
      Wiou, Uiou, biou, Ufw, Ufb, Win, bin, Wmid, bmid, Wout, bout, emo, arena, flag);

  leaf_kernel<<<dim3(512), blk, 0, stream>>>(X, arena, flag, h_all, cbufA);

  // level 7: children = level 8 (65536 rows), c8 in cbufA -> h7, c7 (cbufB)
  level7_kernel<<<dim3(512), blk, 0, stream>>>(h_all + BASE8, cbufA, arena,
                                               h_all + BASE7, cbufB);

  // levels 6..0 + reduction + head, one block per batch element
  fused_kernel<<<dim3(256), blk, FUSED_LDS, stream>>>(h_all, cbufB, arena, flag, d_out);
}